// Round 2
// baseline (532.982 us; speedup 1.0000x reference)
//
#include <hip/hip_runtime.h>

typedef _Float16 f16;
typedef f16  f16x8 __attribute__((ext_vector_type(8)));
typedef f16  f16x4v __attribute__((ext_vector_type(4)));
typedef f16  f16x2v __attribute__((ext_vector_type(2)));
typedef float f32x4 __attribute__((ext_vector_type(4)));

#define SEQ 2048
#define EMB 1024
#define NH  16
#define HD  64
// 0.125 * log2(e): softmax done in exp2 domain (v_exp_f32 is 2^x)
#define SCAL2 0.1803368801111244f

#if __has_builtin(__builtin_amdgcn_exp2f)
#define EXP2(x) __builtin_amdgcn_exp2f(x)
#else
#define EXP2(x) exp2f(x)
#endif

// ---------------- fp32 -> fp16 convert ----------------
__global__ void cvt_f32_f16(const float* __restrict__ src, f16* __restrict__ dst, int n) {
    int i = (blockIdx.x * blockDim.x + threadIdx.x) * 4;
    if (i >= n) return;
    float4 v = *(const float4*)(src + i);
    f16x4v o;
    o[0] = (f16)v.x; o[1] = (f16)v.y; o[2] = (f16)v.z; o[3] = (f16)v.w;
    *(f16x4v*)(dst + i) = o;
}

// ---------------- GEMM: C = A @ B^T (+bias), fp16 in, epilogues ----------------
template<int MODE>
__global__ __launch_bounds__(256) void gemm16(
    const f16* __restrict__ A, const f16* __restrict__ B,
    const float* __restrict__ b0, const float* __restrict__ b1, const float* __restrict__ b2,
    f16* __restrict__ qo, f16* __restrict__ ko, f16* __restrict__ vo,
    float* __restrict__ fo)
{
    __shared__ f16 As[128 * 40];   // +8 pad per row: kills b128 read conflicts
    __shared__ f16 Bs[128 * 40];
    const int tid  = threadIdx.x;
    const int wave = tid >> 6, lane = tid & 63;
    const int g = lane >> 4, li = lane & 15;
    const int wr = wave >> 1, wc = wave & 1;
    const int bm = blockIdx.x * 128, bn = blockIdx.y * 128;

    const f32x4 vzero = {0.f, 0.f, 0.f, 0.f};
    f32x4 acc[4][4];
#pragma unroll
    for (int i = 0; i < 4; ++i)
#pragma unroll
        for (int j = 0; j < 4; ++j) acc[i][j] = vzero;

#pragma unroll 1
    for (int kk = 0; kk < 1024; kk += 32) {
#pragma unroll
        for (int i = 0; i < 2; ++i) {
            int c   = tid + i * 256;
            int row = c >> 2, seg = (c & 3) * 8;
            f16x8 va = *(const f16x8*)(A + (size_t)(bm + row) * 1024 + kk + seg);
            f16x8 vb = *(const f16x8*)(B + (size_t)(bn + row) * 1024 + kk + seg);
            *(f16x8*)(&As[row * 40 + seg]) = va;
            *(f16x8*)(&Bs[row * 40 + seg]) = vb;
        }
        __syncthreads();
        f16x8 af[4];
#pragma unroll
        for (int mi = 0; mi < 4; ++mi)
            af[mi] = *(const f16x8*)(&As[(wr * 64 + mi * 16 + li) * 40 + g * 8]);
#pragma unroll
        for (int ni = 0; ni < 4; ++ni) {
            f16x8 bf = *(const f16x8*)(&Bs[(wc * 64 + ni * 16 + li) * 40 + g * 8]);
#pragma unroll
            for (int mi = 0; mi < 4; ++mi)
                acc[mi][ni] = __builtin_amdgcn_mfma_f32_16x16x32_f16(af[mi], bf, acc[mi][ni], 0, 0, 0);
        }
        __syncthreads();
    }

    // Epilogue. C/D frag: col = lane&15, row = (lane>>4)*4 + reg.
#pragma unroll
    for (int mi = 0; mi < 4; ++mi)
#pragma unroll
        for (int ni = 0; ni < 4; ++ni) {
            int nc = bn + wc * 64 + ni * 16 + li;
#pragma unroll
            for (int r = 0; r < 4; ++r) {
                int   mr = bm + wr * 64 + mi * 16 + g * 4 + r;
                float v  = acc[mi][ni][r];
                if (MODE == 0) {
                    int which = nc >> 10, rr = nc & 1023;
                    int h = rr >> 6, d = rr & 63;
                    int b = mr >> 11, s = mr & 2047;
                    size_t qkidx = ((size_t)((b * NH + h) * SEQ + s)) * HD + d;
                    if (which == 0)      qo[qkidx] = (f16)((v + b0[rr]) * SCAL2);
                    else if (which == 1) ko[qkidx] = (f16)(v + b1[rr]);
                    else                 vo[((size_t)((b * NH + h) * HD + d)) * SEQ + s] = (f16)(v + b2[rr]);
                } else {
                    fo[(size_t)mr * 1024 + nc] = v + b0[nc];
                }
            }
        }
}

// ---------------- Attention (wave = head, two-pass, 2 barriers/chunk) ----------------
// Grid: 256 blocks = (b) x (128 q-tiles of 16 rows). Block: 1024 thr = 16 waves.
// Wave w processes head w: its 16 q-rows x all 2048 k-cols. Pass 1: barrier-free
// online (m,l) per row (lane-local, one shuffle-merge at end). Pass 2: recompute
// QK, P=exp2(s-M)*invL staged to own swizzled LDS region, PV accumulates in regs
// (no cross-wave O reduce); head-mean = cross-region LDS row-sum -> meanw.
__global__ __launch_bounds__(1024) void attn16(
    const f16* __restrict__ Q, const f16* __restrict__ K, const f16* __restrict__ Vt,
    f16* __restrict__ ctx, float* __restrict__ meanw)
{
    __shared__ __align__(16) char pbuf[16][4112];  // per-wave P region (16x128 f16, swizzled)
    const int tid = threadIdx.x;
    const int w = tid >> 6, lane = tid & 63;
    const int g = lane >> 4, li = lane & 15;
    const int b = blockIdx.x >> 7, qt = blockIdx.x & 127;
    const int q0 = qt * 16;
    const int h = w;
    char* myp = pbuf[w];

    const f16* __restrict__ Qh = Q  + ((size_t)((b * NH + h) * SEQ + q0)) * HD;
    const f16* __restrict__ Kh = K  + ((size_t)(b * NH + h)) * SEQ * HD;
    const f16* __restrict__ Vh = Vt + ((size_t)(b * NH + h)) * HD * SEQ;

    // Q A-frags (row = li, k = g*8 .. / +32), reused by both passes
    f16x8 qf0 = *(const f16x8*)(Qh + li * HD + g * 8);
    f16x8 qf1 = *(const f16x8*)(Qh + li * HD + 32 + g * 8);

    const f32x4 vzero = {0.f, 0.f, 0.f, 0.f};

    // ---- pass 1: lane-local online (m,l) per row r (row = g*4+r) ----
    float m[4], l[4];
#pragma unroll
    for (int r = 0; r < 4; ++r) { m[r] = -1e30f; l[r] = 0.f; }

#pragma unroll 1
    for (int kc = 0; kc < 16; ++kc) {
        const f16* kp = Kh + (size_t)(kc * 128 + li) * HD + g * 8;
        f32x4 sc[8];
#pragma unroll
        for (int c = 0; c < 8; ++c) {
            f16x8 k0 = *(const f16x8*)(kp + c * 16 * HD);
            f16x8 k1 = *(const f16x8*)(kp + c * 16 * HD + 32);
            f32x4 t = vzero;
            t = __builtin_amdgcn_mfma_f32_16x16x32_f16(qf0, k0, t, 0, 0, 0);
            t = __builtin_amdgcn_mfma_f32_16x16x32_f16(qf1, k1, t, 0, 0, 0);
            sc[c] = t;
        }
#pragma unroll
        for (int r = 0; r < 4; ++r) {
            float cm = sc[0][r];
#pragma unroll
            for (int c = 1; c < 8; ++c) cm = fmaxf(cm, sc[c][r]);
            float nm = fmaxf(m[r], cm);
            float s = 0.f;
#pragma unroll
            for (int c = 0; c < 8; ++c) s += EXP2(sc[c][r] - nm);
            l[r] = l[r] * EXP2(m[r] - nm) + s;
            m[r] = nm;
        }
    }
    // merge (m,l) across the 16-lane group (butterfly over li)
    float M[4], invl[4];
#pragma unroll
    for (int r = 0; r < 4; ++r) {
        float mm = m[r], ll = l[r];
#pragma unroll
        for (int d = 1; d < 16; d <<= 1) {
            float mo = __shfl_xor(mm, d);
            float lo = __shfl_xor(ll, d);
            float nm = fmaxf(mm, mo);
            ll = ll * EXP2(mm - nm) + lo * EXP2(mo - nm);
            mm = nm;
        }
        M[r] = mm; invl[r] = 1.f / ll;
    }

    // ---- pass 2: P, PV, head-mean ----
    f32x4 o[4];
#pragma unroll
    for (int dt = 0; dt < 4; ++dt) o[dt] = vzero;

    const int swm = (w & 7) << 4;                 // mean-phase swizzle for q-row w
    const int mboff = w * 256 + ((lane * 4) ^ swm);
    float* mrow = meanw + (size_t)b * SEQ * SEQ + (size_t)(q0 + w) * SEQ;

#pragma unroll 1
    for (int kc = 0; kc < 16; ++kc) {
        const f16* kp = Kh + (size_t)(kc * 128 + li) * HD + g * 8;
#pragma unroll
        for (int c = 0; c < 8; ++c) {
            f16x8 k0 = *(const f16x8*)(kp + c * 16 * HD);
            f16x8 k1 = *(const f16x8*)(kp + c * 16 * HD + 32);
            f32x4 t = vzero;
            t = __builtin_amdgcn_mfma_f32_16x16x32_f16(qf0, k0, t, 0, 0, 0);
            t = __builtin_amdgcn_mfma_f32_16x16x32_f16(qf1, k1, t, 0, 0, 0);
#pragma unroll
            for (int r = 0; r < 4; ++r) {
                float p = EXP2(t[r] - M[r]) * invl[r];
                int row = g * 4 + r;
                int off = row * 256 + (((c * 16 + li) * 2) ^ ((row & 7) << 4));
                *(f16*)(myp + off) = (f16)p;
            }
        }
        // PV over this chunk (reads own region only; within-wave ordering is HW-guaranteed)
#pragma unroll
        for (int ks = 0; ks < 4; ++ks) {
            f16x8 pf = *(const f16x8*)(myp + li * 256 + ((ks * 64 + g * 16) ^ ((li & 7) << 4)));
#pragma unroll
            for (int dt = 0; dt < 4; ++dt) {
                f16x8 vf = *(const f16x8*)(Vh + (size_t)(dt * 16 + li) * SEQ + kc * 128 + ks * 32 + g * 8);
                o[dt] = __builtin_amdgcn_mfma_f32_16x16x32_f16(pf, vf, o[dt], 0, 0, 0);
            }
        }
        __syncthreads();   // B1: all waves' P staged
        // head-mean: wave w sums q-row w across all 16 head regions
        {
            float s0 = 0.f, s1 = 0.f;
#pragma unroll
            for (int ww = 0; ww < 16; ++ww) {
                f16x2v pv = *(const f16x2v*)(pbuf[ww] + mboff);
                s0 += (float)pv[0];
                s1 += (float)pv[1];
            }
            float2 out2 = { s0 * 0.0625f, s1 * 0.0625f };
            *(float2*)(mrow + kc * 128 + lane * 2) = out2;
        }
        __syncthreads();   // B2: mean reads done -> regions reusable
    }

    // epilogue: ctx (O frag: row = g*4+r, col = dt*16+li)
#pragma unroll
    for (int dt = 0; dt < 4; ++dt)
#pragma unroll
        for (int r = 0; r < 4; ++r)
            ctx[((size_t)(b * SEQ + q0 + g * 4 + r)) * EMB + h * HD + dt * 16 + li] = (f16)o[dt][r];
}

// ---------------- launch ----------------
extern "C" void kernel_launch(void* const* d_in, const int* in_sizes, int n_in,
                              void* d_out, int out_size, void* d_ws, size_t ws_size,
                              hipStream_t stream) {
    (void)in_sizes; (void)n_in; (void)out_size; (void)ws_size;
    const float* query = (const float*)d_in[0];
    const float* Wq = (const float*)d_in[1];
    const float* bq = (const float*)d_in[2];
    const float* Wk = (const float*)d_in[3];
    const float* bk = (const float*)d_in[4];
    const float* Wv = (const float*)d_in[5];
    const float* bv = (const float*)d_in[6];
    const float* Wo = (const float*)d_in[7];
    const float* bo = (const float*)d_in[8];
    float* out   = (float*)d_out;
    float* meanw = out + (size_t)2 * SEQ * EMB;

    f16* X16   = (f16*)d_ws;
    f16* W16   = X16  + (size_t)4096 * 1024;
    f16* Wo16  = W16  + (size_t)3072 * 1024;
    f16* Q16   = Wo16 + (size_t)1024 * 1024;
    f16* K16   = Q16  + (size_t)2 * NH * SEQ * HD;
    f16* Vt16  = K16  + (size_t)2 * NH * SEQ * HD;
    f16* ctx16 = Vt16 + (size_t)2 * NH * SEQ * HD;

    cvt_f32_f16<<<4096, 256, 0, stream>>>(query, X16, 4194304);
    cvt_f32_f16<<<1024, 256, 0, stream>>>(Wq, W16,            1048576);
    cvt_f32_f16<<<1024, 256, 0, stream>>>(Wk, W16 + 1048576,  1048576);
    cvt_f32_f16<<<1024, 256, 0, stream>>>(Wv, W16 + 2097152,  1048576);
    cvt_f32_f16<<<1024, 256, 0, stream>>>(Wo, Wo16,           1048576);

    gemm16<0><<<dim3(32, 24), 256, 0, stream>>>(X16, W16, bq, bk, bv, Q16, K16, Vt16, nullptr);
    attn16<<<256, 1024, 0, stream>>>(Q16, K16, Vt16, ctx16, meanw);
    gemm16<1><<<dim3(32, 8), 256, 0, stream>>>(ctx16, Wo16, bo, nullptr, nullptr,
                                               nullptr, nullptr, nullptr, out);
}

// Round 5
// 301.345 us; speedup vs baseline: 1.7687x; 1.7687x over previous
//
#include <hip/hip_runtime.h>

typedef _Float16 f16;
typedef f16  f16x8 __attribute__((ext_vector_type(8)));
typedef f16  f16x4v __attribute__((ext_vector_type(4)));
typedef float f32x4 __attribute__((ext_vector_type(4)));

#define SEQ 2048
#define EMB 1024
#define NH  16
#define HD  64
// 0.125 * log2(e): softmax done in exp2 domain (v_exp_f32 is 2^x)
#define SCAL2 0.1803368801111244f

#if __has_builtin(__builtin_amdgcn_exp2f)
#define EXP2(x) __builtin_amdgcn_exp2f(x)
#else
#define EXP2(x) exp2f(x)
#endif

// ---------------- fp32 -> fp16 convert ----------------
__global__ void cvt_f32_f16(const float* __restrict__ src, f16* __restrict__ dst, int n) {
    int i = (blockIdx.x * blockDim.x + threadIdx.x) * 4;
    if (i >= n) return;
    float4 v = *(const float4*)(src + i);
    f16x4v o;
    o[0] = (f16)v.x; o[1] = (f16)v.y; o[2] = (f16)v.z; o[3] = (f16)v.w;
    *(f16x4v*)(dst + i) = o;
}

// ---------------- GEMM: C = A @ B^T (+bias), fp16 in, epilogues ----------------
template<int MODE>
__global__ __launch_bounds__(256) void gemm16(
    const f16* __restrict__ A, const f16* __restrict__ B,
    const float* __restrict__ b0, const float* __restrict__ b1, const float* __restrict__ b2,
    f16* __restrict__ qo, f16* __restrict__ ko, f16* __restrict__ vo,
    float* __restrict__ fo)
{
    __shared__ f16 As[128 * 40];   // +8 pad per row: kills b128 read conflicts
    __shared__ f16 Bs[128 * 40];
    const int tid  = threadIdx.x;
    const int wave = tid >> 6, lane = tid & 63;
    const int g = lane >> 4, li = lane & 15;
    const int wr = wave >> 1, wc = wave & 1;
    const int bm = blockIdx.x * 128, bn = blockIdx.y * 128;

    const f32x4 vzero = {0.f, 0.f, 0.f, 0.f};
    f32x4 acc[4][4];
#pragma unroll
    for (int i = 0; i < 4; ++i)
#pragma unroll
        for (int j = 0; j < 4; ++j) acc[i][j] = vzero;

#pragma unroll 1
    for (int kk = 0; kk < 1024; kk += 32) {
#pragma unroll
        for (int i = 0; i < 2; ++i) {
            int c   = tid + i * 256;
            int row = c >> 2, seg = (c & 3) * 8;
            f16x8 va = *(const f16x8*)(A + (size_t)(bm + row) * 1024 + kk + seg);
            f16x8 vb = *(const f16x8*)(B + (size_t)(bn + row) * 1024 + kk + seg);
            *(f16x8*)(&As[row * 40 + seg]) = va;
            *(f16x8*)(&Bs[row * 40 + seg]) = vb;
        }
        __syncthreads();
        f16x8 af[4];
#pragma unroll
        for (int mi = 0; mi < 4; ++mi)
            af[mi] = *(const f16x8*)(&As[(wr * 64 + mi * 16 + li) * 40 + g * 8]);
#pragma unroll
        for (int ni = 0; ni < 4; ++ni) {
            f16x8 bf = *(const f16x8*)(&Bs[(wc * 64 + ni * 16 + li) * 40 + g * 8]);
#pragma unroll
            for (int mi = 0; mi < 4; ++mi)
                acc[mi][ni] = __builtin_amdgcn_mfma_f32_16x16x32_f16(af[mi], bf, acc[mi][ni], 0, 0, 0);
        }
        __syncthreads();
    }

    // Epilogue. C/D frag: col = lane&15, row = (lane>>4)*4 + reg.
#pragma unroll
    for (int mi = 0; mi < 4; ++mi)
#pragma unroll
        for (int ni = 0; ni < 4; ++ni) {
            int nc = bn + wc * 64 + ni * 16 + li;
#pragma unroll
            for (int r = 0; r < 4; ++r) {
                int   mr = bm + wr * 64 + mi * 16 + g * 4 + r;
                float v  = acc[mi][ni][r];
                if (MODE == 0) {
                    int which = nc >> 10, rr = nc & 1023;
                    int h = rr >> 6, d = rr & 63;
                    int b = mr >> 11, s = mr & 2047;
                    size_t qkidx = ((size_t)((b * NH + h) * SEQ + s)) * HD + d;
                    if (which == 0)      qo[qkidx] = (f16)((v + b0[rr]) * SCAL2);
                    else if (which == 1) ko[qkidx] = (f16)(v + b1[rr]);
                    else                 vo[((size_t)((b * NH + h) * HD + d)) * SEQ + s] = (f16)(v + b2[rr]);
                } else {
                    fo[(size_t)mr * 1024 + nc] = v + b0[nc];
                }
            }
        }
}

// ---------------- Flash attention: ctx + per-row stats ----------------
// Grid 512 = (qt 0..15) x (b,h 0..31). Block 512 thr = 8 waves, wave w = q-rows
// qb+w*16..+16. K chunk [128k x 64d] and V chunk [64d x 128k] staged in shared,
// XOR-swizzled LDS; online softmax with per-chunk 16-lane max merge (P rows get
// a consistent scale before the PV MFMA). Async-stage split: global loads for
// chunk i+1 issued before compute of chunk i, ds_write after the barrier.
__global__ __launch_bounds__(512) void attn_flash(
    const f16* __restrict__ Q, const f16* __restrict__ K, const f16* __restrict__ Vt,
    f16* __restrict__ ctx, float* __restrict__ Mb, float* __restrict__ Lb)
{
    __shared__ __align__(16) char KsB[128 * 128];  // row k: 64 f16 = 128B, xor (k&7)<<4
    __shared__ __align__(16) char VsB[64 * 256];   // row d: 128 f16 = 256B, xor (d&15)<<4
    __shared__ __align__(16) char Ps[8][4096];     // per-wave P: row q: 128 f16, xor (q&7)<<4

    const int tid = threadIdx.x;
    const int w = tid >> 6, lane = tid & 63;
    const int g = lane >> 4, li = lane & 15;
    const int bh = blockIdx.x & 31, qt = blockIdx.x >> 5;
    const int b = bh >> 4, h = bh & 15;
    const int qb = qt * 128;
    char* myp = Ps[w];

    const f16* __restrict__ Qh = Q  + ((size_t)(bh * SEQ + qb + w * 16)) * HD;
    const f16* __restrict__ Kh = K  + (size_t)bh * SEQ * HD;
    const f16* __restrict__ Vh = Vt + (size_t)bh * HD * SEQ;

    // staging geometry (thread tid):
    const int rk = tid >> 2, sk = (tid & 3) * 32;          // K: row 0..127, byte seg
    const int dv = tid >> 3, sv = (tid & 7) * 32;          // V: row d 0..63, byte seg
    const int swk = (rk & 7) << 4, swv = (dv & 15) << 4;
    char* ldsK0 = KsB + rk * 128 + ((sk)      ^ swk);
    char* ldsK1 = KsB + rk * 128 + ((sk + 16) ^ swk);
    char* ldsV0 = VsB + dv * 256 + ((sv)      ^ swv);
    char* ldsV1 = VsB + dv * 256 + ((sv + 16) ^ swv);
    const f16* gK = Kh + (size_t)rk * HD + (sk >> 1);
    const f16* gV = Vh + (size_t)dv * SEQ + (sv >> 1);

    f16x8 stK0, stK1, stV0, stV1;
#define LOADR(kc) do { \
        const f16* p0 = gK + (size_t)(kc) * 128 * HD; \
        stK0 = *(const f16x8*)(p0); stK1 = *(const f16x8*)(p0 + 8); \
        const f16* p1 = gV + (kc) * 128; \
        stV0 = *(const f16x8*)(p1); stV1 = *(const f16x8*)(p1 + 8); \
    } while (0)
#define WRLDS() do { \
        *(f16x8*)ldsK0 = stK0; *(f16x8*)ldsK1 = stK1; \
        *(f16x8*)ldsV0 = stV0; *(f16x8*)ldsV1 = stV1; \
    } while (0)

    // Q frags: row li, d = g*8 / +32
    f16x8 qf0 = *(const f16x8*)(Qh + li * HD + g * 8);
    f16x8 qf1 = *(const f16x8*)(Qh + li * HD + 32 + g * 8);

    const f32x4 vzero = {0.f, 0.f, 0.f, 0.f};
    f32x4 o[4];
#pragma unroll
    for (int dt = 0; dt < 4; ++dt) o[dt] = vzero;
    float m[4], l[4];
#pragma unroll
    for (int r = 0; r < 4; ++r) { m[r] = -1e30f; l[r] = 0.f; }

    const int swp = (li & 7) << 4;

    LOADR(0);
    WRLDS();
    __syncthreads();

#pragma unroll 1
    for (int kc = 0; kc < 16; ++kc) {
        if (kc < 15) LOADR(kc + 1);

        // QK: 8 col-tiles of 16 k
        f32x4 sc[8];
#pragma unroll
        for (int c = 0; c < 8; ++c) {
            const char* kr = KsB + (c * 16 + li) * 128;
            f16x8 k0 = *(const f16x8*)(kr + ((g * 16)      ^ swp));
            f16x8 k1 = *(const f16x8*)(kr + ((g * 16 + 64) ^ swp));
            f32x4 t = vzero;
            t = __builtin_amdgcn_mfma_f32_16x16x32_f16(qf0, k0, t, 0, 0, 0);
            t = __builtin_amdgcn_mfma_f32_16x16x32_f16(qf1, k1, t, 0, 0, 0);
            sc[c] = t;
        }

        // online softmax (rows q = g*4+r; merge chunk max over the 16 li-lanes)
#pragma unroll
        for (int r = 0; r < 4; ++r) {
            float cm = sc[0][r];
#pragma unroll
            for (int c = 1; c < 8; ++c) cm = fmaxf(cm, sc[c][r]);
#pragma unroll
            for (int d = 1; d < 16; d <<= 1) cm = fmaxf(cm, __shfl_xor(cm, d));
            float nm = fmaxf(m[r], cm);
            float sca = EXP2(m[r] - nm);
            m[r] = nm;
            int q = g * 4 + r;
            char* prow = myp + q * 256;
            int swq = (q & 7) << 4;
            float ps = 0.f;
#pragma unroll
            for (int c = 0; c < 8; ++c) {
                float p = EXP2(sc[c][r] - nm);
                ps += p;
                *(f16*)(prow + ((c * 32 + li * 2) ^ swq)) = (f16)p;
            }
            l[r] = l[r] * sca + ps;
#pragma unroll
            for (int dt = 0; dt < 4; ++dt) o[dt][r] *= sca;
        }

        // PV over this chunk
#pragma unroll
        for (int ks = 0; ks < 4; ++ks) {
            f16x8 pf = *(const f16x8*)(myp + li * 256 + ((ks * 64 + g * 16) ^ swp));
#pragma unroll
            for (int dt = 0; dt < 4; ++dt) {
                f16x8 vf = *(const f16x8*)(VsB + (dt * 16 + li) * 256 + ((ks * 64 + g * 16) ^ (li << 4)));
                o[dt] = __builtin_amdgcn_mfma_f32_16x16x32_f16(pf, vf, o[dt], 0, 0, 0);
            }
        }

        if (kc < 15) {
            __syncthreads();   // everyone done reading Ks/Vs
            WRLDS();
            __syncthreads();   // next chunk staged
        }
    }

    // merge l across the 16 li-lanes (m already merged each chunk)
    float invl[4];
#pragma unroll
    for (int r = 0; r < 4; ++r) {
        float s = l[r];
#pragma unroll
        for (int d = 1; d < 16; d <<= 1) s += __shfl_xor(s, d);
        invl[r] = 1.f / s;
    }

    // ctx + stats
#pragma unroll
    for (int dt = 0; dt < 4; ++dt)
#pragma unroll
        for (int r = 0; r < 4; ++r)
            ctx[((size_t)(b * SEQ + qb + w * 16 + g * 4 + r)) * EMB + h * HD + dt * 16 + li]
                = (f16)(o[dt][r] * invl[r]);
    if (li == 0) {
#pragma unroll
        for (int r = 0; r < 4; ++r) {
            int qi = bh * SEQ + qb + w * 16 + g * 4 + r;
            Mb[qi] = m[r];
            Lb[qi] = invl[r];
        }
    }
#undef LOADR
#undef WRLDS
}

// ---------------- Head-mean of attention weights ----------------
// Grid 512 = (b, qt 0..15, kt 0..15), 128x128 output tile, heads looped inside
// (mean accumulates in registers). Q/K tiles LDS-staged per head, shared by all
// 8 waves; stats staged once.
__global__ __launch_bounds__(512) void attn_mean(
    const f16* __restrict__ Q, const f16* __restrict__ K,
    const float* __restrict__ Mb, const float* __restrict__ Lb,
    float* __restrict__ meanw)
{
    __shared__ __align__(16) char Qs[128 * 128];  // row q: 64 f16 = 128B, xor (q&7)<<4
    __shared__ __align__(16) char Ks[128 * 128];  // row k: same
    __shared__ float Ms[NH][128], Ls[NH][128];

    const int tid = threadIdx.x;
    const int w = tid >> 6, lane = tid & 63;
    const int g = lane >> 4, li = lane & 15;
    const int bid = blockIdx.x;
    const int b = bid >> 8, qt = (bid >> 4) & 15, kt = bid & 15;
    const int q0 = qt * 128, k0 = kt * 128;

    // stage stats for all heads of this q-block
    {
        int hh = tid >> 5, qq = (tid & 31) * 4;
        const float* mp = Mb + (size_t)(b * NH + hh) * SEQ + q0 + qq;
        const float* lp = Lb + (size_t)(b * NH + hh) * SEQ + q0 + qq;
        *(float4*)(&Ms[hh][qq]) = *(const float4*)mp;
        *(float4*)(&Ls[hh][qq]) = *(const float4*)lp;
    }

    const int rr = tid >> 2, ss = (tid & 3) * 32;
    const int sw = (rr & 7) << 4;
    char* ldsQ0 = Qs + rr * 128 + ((ss)      ^ sw);
    char* ldsQ1 = Qs + rr * 128 + ((ss + 16) ^ sw);
    char* ldsK0 = Ks + rr * 128 + ((ss)      ^ sw);
    char* ldsK1 = Ks + rr * 128 + ((ss + 16) ^ sw);
    const f16* gQ = Q + (size_t)(b * NH * SEQ + q0 + rr) * HD + (ss >> 1);
    const f16* gK = K + (size_t)(b * NH * SEQ + k0 + rr) * HD + (ss >> 1);

    f16x8 sq0, sq1, sk0, sk1;
#define LOADR(h) do { \
        const f16* p0 = gQ + (size_t)(h) * SEQ * HD; \
        sq0 = *(const f16x8*)(p0); sq1 = *(const f16x8*)(p0 + 8); \
        const f16* p1 = gK + (size_t)(h) * SEQ * HD; \
        sk0 = *(const f16x8*)(p1); sk1 = *(const f16x8*)(p1 + 8); \
    } while (0)
#define WRLDS() do { \
        *(f16x8*)ldsQ0 = sq0; *(f16x8*)ldsQ1 = sq1; \
        *(f16x8*)ldsK0 = sk0; *(f16x8*)ldsK1 = sk1; \
    } while (0)

    f32x4 macc[8];
#pragma unroll
    for (int c = 0; c < 8; ++c) macc[c] = (f32x4){0.f, 0.f, 0.f, 0.f};

    const int swp = (li & 7) << 4;
    const f32x4 vzero = {0.f, 0.f, 0.f, 0.f};

    LOADR(0);
    WRLDS();
    __syncthreads();

#pragma unroll 1
    for (int h = 0; h < NH; ++h) {
        if (h < NH - 1) LOADR(h + 1);

        const char* qr = Qs + (w * 16 + li) * 128;
        f16x8 af0 = *(const f16x8*)(qr + ((g * 16)      ^ swp));
        f16x8 af1 = *(const f16x8*)(qr + ((g * 16 + 64) ^ swp));

#pragma unroll
        for (int c = 0; c < 8; ++c) {
            const char* kr = Ks + (c * 16 + li) * 128;
            f16x8 k0 = *(const f16x8*)(kr + ((g * 16)      ^ swp));
            f16x8 k1 = *(const f16x8*)(kr + ((g * 16 + 64) ^ swp));
            f32x4 t = vzero;
            t = __builtin_amdgcn_mfma_f32_16x16x32_f16(af0, k0, t, 0, 0, 0);
            t = __builtin_amdgcn_mfma_f32_16x16x32_f16(af1, k1, t, 0, 0, 0);
#pragma unroll
            for (int r = 0; r < 4; ++r) {
                int q = w * 16 + g * 4 + r;
                macc[c][r] += EXP2(t[r] - Ms[h][q]) * Ls[h][q];
            }
        }

        __syncthreads();
        if (h < NH - 1) {
            WRLDS();
        }
        __syncthreads();
    }

    float* mw = meanw + (size_t)b * SEQ * SEQ + (size_t)(q0 + w * 16 + g * 4) * SEQ + k0;
#pragma unroll
    for (int r = 0; r < 4; ++r)
#pragma unroll
        for (int c = 0; c < 8; ++c)
            mw[(size_t)r * SEQ + c * 16 + li] = macc[c][r] * 0.0625f;
#undef LOADR
#undef WRLDS
}

// ---------------- launch ----------------
extern "C" void kernel_launch(void* const* d_in, const int* in_sizes, int n_in,
                              void* d_out, int out_size, void* d_ws, size_t ws_size,
                              hipStream_t stream) {
    (void)in_sizes; (void)n_in; (void)out_size; (void)ws_size;
    const float* query = (const float*)d_in[0];
    const float* Wq = (const float*)d_in[1];
    const float* bq = (const float*)d_in[2];
    const float* Wk = (const float*)d_in[3];
    const float* bk = (const float*)d_in[4];
    const float* Wv = (const float*)d_in[5];
    const float* bv = (const float*)d_in[6];
    const float* Wo = (const float*)d_in[7];
    const float* bo = (const float*)d_in[8];
    float* out   = (float*)d_out;
    float* meanw = out + (size_t)2 * SEQ * EMB;

    f16* X16   = (f16*)d_ws;
    f16* W16   = X16  + (size_t)4096 * 1024;
    f16* Wo16  = W16  + (size_t)3072 * 1024;
    f16* Q16   = Wo16 + (size_t)1024 * 1024;
    f16* K16   = Q16  + (size_t)2 * NH * SEQ * HD;
    f16* Vt16  = K16  + (size_t)2 * NH * SEQ * HD;
    f16* ctx16 = Vt16 + (size_t)2 * NH * SEQ * HD;
    float* Mb  = (float*)(ctx16 + (size_t)2 * NH * SEQ * HD);
    float* Lb  = Mb + (size_t)2 * NH * SEQ;

    cvt_f32_f16<<<4096, 256, 0, stream>>>(query, X16, 4194304);
    cvt_f32_f16<<<1024, 256, 0, stream>>>(Wq, W16,            1048576);
    cvt_f32_f16<<<1024, 256, 0, stream>>>(Wk, W16 + 1048576,  1048576);
    cvt_f32_f16<<<1024, 256, 0, stream>>>(Wv, W16 + 2097152,  1048576);
    cvt_f32_f16<<<1024, 256, 0, stream>>>(Wo, Wo16,           1048576);

    gemm16<0><<<dim3(32, 24), 256, 0, stream>>>(X16, W16, bq, bk, bv, Q16, K16, Vt16, nullptr);
    attn_flash<<<512, 512, 0, stream>>>(Q16, K16, Vt16, ctx16, Mb, Lb);
    attn_mean<<<512, 512, 0, stream>>>(Q16, K16, Mb, Lb, meanw);
    gemm16<1><<<dim3(32, 8), 256, 0, stream>>>(ctx16, Wo16, bo, nullptr, nullptr,
                                               nullptr, nullptr, nullptr, out);
}